// Round 7
// baseline (2356.137 us; speedup 1.0000x reference)
//
#include <hip/hip_runtime.h>
#include <hip/hip_bf16.h>
#include <math.h>

#define N_NODES 100000
#define DD 128
#define MAXDEG 16
#define HIDW 256
#define NBLOCKS 5
#define NGRAPH 2048
#define CATW 768   // D*(BLOCKS+1)

typedef __attribute__((ext_vector_type(8))) short short8;
typedef __attribute__((ext_vector_type(4))) float f32x4;

__device__ __forceinline__ float b2f(ushort u) {
    union { unsigned int i; float f; } x; x.i = ((unsigned int)u) << 16; return x.f;
}
__device__ __forceinline__ ushort f2b(float f) {
    unsigned int x = __float_as_uint(f);
    unsigned int r = (x + 0x7fffu + ((x >> 16) & 1u)) >> 16;
    return (ushort)r;
}
// order-preserving float<->uint for atomicMin
__device__ __forceinline__ unsigned int encf(float f) {
    unsigned int b = __float_as_uint(f);
    return (b & 0x80000000u) ? ~b : (b | 0x80000000u);
}
__device__ __forceinline__ float decf(unsigned int e) {
    return __uint_as_float((e & 0x80000000u) ? (e & 0x7fffffffu) : ~e);
}

// ---------- init: h = x (fp32), hb = bf16(x) ----------
__global__ __launch_bounds__(256)
void k_init(const float* __restrict__ x, float* __restrict__ h, ushort* __restrict__ hb)
{
    size_t i = ((size_t)blockIdx.x * 256 + threadIdx.x) * 4;
    float4 v = *reinterpret_cast<const float4*>(x + i);
    *reinterpret_cast<float4*>(h + i) = v;
    ushort4 u;
    u.x = f2b(v.x); u.y = f2b(v.y); u.z = f2b(v.z); u.w = f2b(v.w);
    *reinterpret_cast<ushort4*>(hb + i) = u;
}

// ---------- setup: colmin bufs to +inf(enc), bn accumulators to 0 ----------
__global__ void k_setup(unsigned int* __restrict__ cmin, float* __restrict__ bnacc)
{
    int t = threadIdx.x;
    for (int i = t; i < 6 * DD; i += 256) cmin[i] = 0xFF800000u;  // enc(+inf)
    for (int i = t; i < NBLOCKS * 2 * DD; i += 256) bnacc[i] = 0.f;
}

// ---------- batched convert + transpose: src (cnt,K,M) fp32 -> dst (cnt,M,K) bf16 ----------
__global__ __launch_bounds__(256)
void k_convT(const float* __restrict__ src, ushort* __restrict__ dst, int K, int M, int total)
{
    int id = blockIdx.x * 256 + threadIdx.x;
    if (id >= total) return;
    int km = K * M;
    int b = id / km, rem = id - b * km;
    int m = rem / K, k = rem - m * K;
    dst[(size_t)b * km + (size_t)m * K + k] = f2b(src[(size_t)b * km + (size_t)k * M + m]);
}

// ---------- column min over rows of x (fp32, startup only) ----------
__global__ __launch_bounds__(256)
void k_colmin_part(const float* __restrict__ h, float* __restrict__ part, int nrows)
{
    int t = threadIdx.x;
    int c = t & 127, half = t >> 7;
    int r0 = blockIdx.x * 256;
    int rend = r0 + 256; if (rend > nrows) rend = nrows;
    float m = INFINITY;
    for (int r = r0 + half; r < rend; r += 2)
        m = fminf(m, h[(size_t)r * DD + c]);
    __shared__ float sm[256];
    sm[t] = m;
    __syncthreads();
    if (half == 0) part[(size_t)blockIdx.x * DD + c] = fminf(sm[c], sm[c + 128]);
}

__global__ void k_colmin_fin(const float* __restrict__ part, unsigned int* __restrict__ colmin, int nb)
{
    int c = threadIdx.x; // 128 threads
    float m = INFINITY;
    for (int b = 0; b < nb; ++b) m = fminf(m, part[(size_t)b * DD + c]);
    colmin[c] = encf(m);
}

// ---------- aggregation (bf16): 16 nodes/block, 16 lanes/node, 8 cols/lane ----------
__global__ __launch_bounds__(256)
void k_aggregate_b(const ushort* __restrict__ hb, const int* __restrict__ nbr,
                   const unsigned int* __restrict__ cmin, ushort* __restrict__ A)
{
    int t = threadIdx.x;
    int node = blockIdx.x * 16 + (t >> 4);
    int c0 = (t & 15) * 8;
    const int* row = nbr + (size_t)node * MAXDEG;
    float s[8], mx[8];
#pragma unroll
    for (int q = 0; q < 8; ++q) { s[q] = 0.f; mx[q] = -INFINITY; }
    int cnt = 0;
#pragma unroll
    for (int j = 0; j < MAXDEG; ++j) {
        int id = row[j];
        if (id >= 0) {
            uint4 v = *reinterpret_cast<const uint4*>(hb + (size_t)id * DD + c0);
            unsigned int w0 = v.x, w1 = v.y, w2 = v.z, w3 = v.w;
            float f0 = __uint_as_float(w0 << 16),  f1 = __uint_as_float(w0 & 0xffff0000u);
            float f2 = __uint_as_float(w1 << 16),  f3 = __uint_as_float(w1 & 0xffff0000u);
            float f4 = __uint_as_float(w2 << 16),  f5 = __uint_as_float(w2 & 0xffff0000u);
            float f6 = __uint_as_float(w3 << 16),  f7 = __uint_as_float(w3 & 0xffff0000u);
            s[0] += f0; s[1] += f1; s[2] += f2; s[3] += f3;
            s[4] += f4; s[5] += f5; s[6] += f6; s[7] += f7;
            mx[0] = fmaxf(mx[0], f0); mx[1] = fmaxf(mx[1], f1);
            mx[2] = fmaxf(mx[2], f2); mx[3] = fmaxf(mx[3], f3);
            mx[4] = fmaxf(mx[4], f4); mx[5] = fmaxf(mx[5], f5);
            mx[6] = fmaxf(mx[6], f6); mx[7] = fmaxf(mx[7], f7);
            ++cnt;
        }
    }
    if (cnt == 0) {
#pragma unroll
        for (int q = 0; q < 8; ++q) mx[q] = decf(cmin[c0 + q]);
    }
    short8 vs, vm;
#pragma unroll
    for (int q = 0; q < 8; ++q) { vs[q] = (short)f2b(s[q]); vm[q] = (short)f2b(mx[q]); }
    *reinterpret_cast<short8*>(A + (size_t)node * (2 * DD) + c0) = vs;
    *reinterpret_cast<short8*>(A + (size_t)node * (2 * DD) + DD + c0) = vm;
}

// ---------- wave-independent fused MLP, 16 rows/wave ----------
// Grid 1563 blocks x 4 waves = 6250 waves (~6 blocks/CU available).
// Weights streamed from L2 as B-frags; z/t transposes via wave-private LDS
// (5KB/wave, 20KB/block -> LDS allows 8 blocks/CU); no block barriers.
__global__ __launch_bounds__(256, 4)
void k_fused_wave(const ushort* __restrict__ Ag, const float* __restrict__ h,
                  const ushort* __restrict__ mW, const ushort* __restrict__ w1,
                  const ushort* __restrict__ w2, const float* __restrict__ mb,
                  const float* __restrict__ b1, const float* __restrict__ b2,
                  const float* __restrict__ eps_ptr, float* __restrict__ uf,
                  float* __restrict__ bnacc)
{
    __shared__ __align__(16) char pool[20480];
    const int t = threadIdx.x;
    const int lane = t & 63, wave = t >> 6;
    char* zs = pool + wave * 5120;         // [16][128] bf16 = 4KB, XOR-swz
    char* ts = zs + 4096;                  // [16][32]  bf16 = 1KB, XOR-swz
    const int lr = lane & 15;
    const int lg = lane >> 4;              // k-chunk group 0..3
    const int r0 = blockIdx.x * 64 + wave * 16;
    const float alpha = 1.f + *eps_ptr;

    // ---- phase A: z(16x128) = Ag(16x256) @ mW^T + mb + alpha*h ----
    f32x4 acc[8];
#pragma unroll
    for (int n = 0; n < 8; ++n) acc[n] = (f32x4)(0.f);

    const ushort* agp = Ag + (size_t)(r0 + lr) * 256 + lg * 8;
    const ushort* mwp = mW + (size_t)lr * 256 + lg * 8;
    const bool ok0 = (r0 + lr) < N_NODES;
#pragma unroll
    for (int k32 = 0; k32 < 8; ++k32) {
        short8 af = {};
        if (ok0) af = *reinterpret_cast<const short8*>(agp + k32 * 32);
        short8 bq[8];
#pragma unroll
        for (int n = 0; n < 8; ++n)
            bq[n] = *reinterpret_cast<const short8*>(mwp + (size_t)n * 16 * 256 + k32 * 32);
#pragma unroll
        for (int n = 0; n < 8; ++n)
            acc[n] = __builtin_amdgcn_mfma_f32_16x16x32_bf16(af, bq[n], acc[n], 0, 0, 0);
    }
    // epilogue A -> zs
#pragma unroll
    for (int j = 0; j < 4; ++j) {
        int lrow = lg * 4 + j;
        int grow = r0 + lrow;
#pragma unroll
        for (int n = 0; n < 8; ++n) {
            int col = n * 16 + lr;
            float z = acc[n][j] + mb[col];
            if (grow < N_NODES) z += alpha * h[(size_t)grow * DD + col];
            int byte = (lrow << 8) | (col << 1);
            byte ^= (lrow & 7) << 4;
            *reinterpret_cast<ushort*>(zs + byte) = f2b(z);
        }
    }
    asm volatile("s_waitcnt lgkmcnt(0)" ::: "memory");
    __builtin_amdgcn_sched_barrier(0);

    // ---- phase B+C interleaved per 32-hid chunk ----
    f32x4 au[8];
#pragma unroll
    for (int n = 0; n < 8; ++n) au[n] = (f32x4)(0.f);

    const ushort* w1p = w1 + (size_t)lr * 128 + lg * 8;
    const ushort* w2p = w2 + (size_t)lr * 256 + lg * 8;
    for (int hc = 0; hc < 8; ++hc) {
        // B: t_chunk(16x32) = relu(z @ w1[hc*32..][:]^T + b1)
        f32x4 at[2];
        at[0] = (f32x4)(0.f); at[1] = (f32x4)(0.f);
#pragma unroll
        for (int k32 = 0; k32 < 4; ++k32) {
            int byte = (lr << 8) | (k32 << 6) | (lg << 4);
            byte ^= (lr & 7) << 4;
            short8 az = *reinterpret_cast<const short8*>(zs + byte);
#pragma unroll
            for (int n2 = 0; n2 < 2; ++n2) {
                short8 bq = *reinterpret_cast<const short8*>(
                    w1p + (size_t)(hc * 32 + n2 * 16) * 128 + k32 * 32);
                at[n2] = __builtin_amdgcn_mfma_f32_16x16x32_bf16(az, bq, at[n2], 0, 0, 0);
            }
        }
        // t chunk -> ts (bf16)
#pragma unroll
        for (int j = 0; j < 4; ++j) {
            int lrow = lg * 4 + j;
#pragma unroll
            for (int n2 = 0; n2 < 2; ++n2) {
                int hcol = n2 * 16 + lr;
                float tv = fmaxf(at[n2][j] + b1[hc * 32 + hcol], 0.f);
                int byte = (lrow << 6) | (hcol << 1);
                byte ^= (lrow & 3) << 4;
                *reinterpret_cast<ushort*>(ts + byte) = f2b(tv);
            }
        }
        asm volatile("s_waitcnt lgkmcnt(0)" ::: "memory");
        __builtin_amdgcn_sched_barrier(0);
        // C: au += t_chunk @ w2[:, hc*32..]^T
        int byte = (lr << 6) | (lg << 4);
        byte ^= (lr & 3) << 4;
        short8 atf = *reinterpret_cast<const short8*>(ts + byte);
#pragma unroll
        for (int n = 0; n < 8; ++n) {
            short8 bq = *reinterpret_cast<const short8*>(
                w2p + (size_t)n * 16 * 256 + hc * 32);
            au[n] = __builtin_amdgcn_mfma_f32_16x16x32_bf16(atf, bq, au[n], 0, 0, 0);
        }
        asm volatile("s_waitcnt lgkmcnt(0)" ::: "memory");
        __builtin_amdgcn_sched_barrier(0);
    }

    // ---- epilogue C: u store (fp32) + BN partial sums ----
    float e1[8], e2[8];
#pragma unroll
    for (int n = 0; n < 8; ++n) { e1[n] = 0.f; e2[n] = 0.f; }
#pragma unroll
    for (int j = 0; j < 4; ++j) {
        int grow = r0 + lg * 4 + j;
        if (grow >= N_NODES) continue;
#pragma unroll
        for (int n = 0; n < 8; ++n) {
            int col = n * 16 + lr;
            float u = fmaxf(au[n][j] + b2[col], 0.f);
            uf[(size_t)grow * DD + col] = u;
            e1[n] += u; e2[n] += u * u;
        }
    }
#pragma unroll
    for (int n = 0; n < 8; ++n) {
        float a = e1[n], b = e2[n];
        a += __shfl_xor(a, 16); b += __shfl_xor(b, 16);
        a += __shfl_xor(a, 32); b += __shfl_xor(b, 32);
        if (lg == 0) {
            atomicAdd(&bnacc[n * 16 + lr], a);
            atomicAdd(&bnacc[128 + n * 16 + lr], b);
        }
    }
}

__global__ void k_bn_fin(const float* __restrict__ part, int nb, float inv_n,
                         float* __restrict__ mean, float* __restrict__ inv)
{
    int c = threadIdx.x; // 128 threads
    float s1 = 0.f, s2 = 0.f;
    for (int b = 0; b < nb; ++b) {
        s1 += part[(size_t)b * 256 + c];
        s2 += part[(size_t)b * 256 + 128 + c];
    }
    float m = s1 * inv_n;
    float v = s2 * inv_n - m * m;
    mean[c] = m;
    inv[c] = rsqrtf(v + 1e-5f);
}

// ---------- BN apply + h update + hb mirror + colmin(next) + segmented scan into G ----------
__global__ __launch_bounds__(256)
void k_bn_apply_scan(const float* __restrict__ u, float* __restrict__ h,
                     ushort* __restrict__ hb,
                     const float* __restrict__ mean, const float* __restrict__ inv,
                     const float* __restrict__ gam, const float* __restrict__ bet,
                     const int* __restrict__ mem, float* __restrict__ G,
                     unsigned int* __restrict__ cmin_next,
                     int colbase, int nrows)
{
    int t = threadIdx.x;
    int c = t & 127, half = t >> 7;
    int r0 = blockIdx.x * 128;
    int rend = r0 + 128; if (rend > nrows) rend = nrows;
    float mu = mean[c], iv = inv[c], g = gam[c], b = bet[c];
    float accv = 0.f, lmin = INFINITY;
    int curg = -1;
    for (int r = r0 + half; r < rend; r += 2) {
        float z = g * (u[(size_t)r * DD + c] - mu) * iv + b;
        float hn = h[(size_t)r * DD + c] + z;
        h[(size_t)r * DD + c] = hn;
        hb[(size_t)r * DD + c] = f2b(hn);
        lmin = fminf(lmin, hn);
        int gg = mem[r];
        if (gg != curg) {
            if (curg >= 0) atomicAdd(&G[(size_t)curg * CATW + colbase + c], accv);
            curg = gg; accv = 0.f;
        }
        accv += z;
    }
    if (curg >= 0) atomicAdd(&G[(size_t)curg * CATW + colbase + c], accv);
    __shared__ float sm[256];
    sm[t] = lmin;
    __syncthreads();
    if (half == 0) atomicMin(&cmin_next[c], encf(fminf(sm[c], sm[c + 128])));
}

// ---------- segmented scan-add of x (fp32) into G cols [0,128) ----------
__global__ __launch_bounds__(256)
void k_scan_x(const float* __restrict__ x, const int* __restrict__ mem,
              float* __restrict__ G, int nrows)
{
    int t = threadIdx.x;
    int c = t & 127, half = t >> 7;
    int r0 = blockIdx.x * 128;
    int rend = r0 + 128; if (rend > nrows) rend = nrows;
    float accv = 0.f;
    int curg = -1;
    for (int r = r0 + half; r < rend; r += 2) {
        float z = x[(size_t)r * DD + c];
        int gg = mem[r];
        if (gg != curg) {
            if (curg >= 0) atomicAdd(&G[(size_t)curg * CATW + c], accv);
            curg = gg; accv = 0.f;
        }
        accv += z;
    }
    if (curg >= 0) atomicAdd(&G[(size_t)curg * CATW + c], accv);
}

// ---------- BN stats partials from fp32 (readout path) ----------
__global__ __launch_bounds__(256)
void k_bn_part(const float* __restrict__ u, float* __restrict__ part, int nrows)
{
    int t = threadIdx.x;
    int c = t & 127, half = t >> 7;
    int r0 = blockIdx.x * 256;
    int rend = r0 + 256; if (rend > nrows) rend = nrows;
    float s1 = 0.f, s2 = 0.f;
    for (int r = r0 + half; r < rend; r += 2) {
        float v = u[(size_t)r * DD + c];
        s1 += v; s2 += v * v;
    }
    __shared__ float sh1[256], sh2[256];
    sh1[t] = s1; sh2[t] = s2;
    __syncthreads();
    if (half == 0) {
        part[(size_t)blockIdx.x * 256 + c]       = sh1[c] + sh1[c + 128];
        part[(size_t)blockIdx.x * 256 + 128 + c] = sh2[c] + sh2[c + 128];
    }
}

// ---------- readout dense0: (2048x768)@(768x256), 8 rows/block ----------
__global__ __launch_bounds__(256)
void k_read0(const float* __restrict__ G, const float* __restrict__ W,
             const float* __restrict__ b, float* __restrict__ o)
{
    __shared__ float As[8][CATW];
    int t = threadIdx.x;
    int rb = blockIdx.x * 8;
#pragma unroll
    for (int p = 0; p < 6; ++p) {
        int idx = p * 256 + t;         // float4 index; 8*768/4 = 1536
        int r = idx / 192, k4 = idx - r * 192;
        float4 v = *reinterpret_cast<const float4*>(G + (size_t)(rb + r) * CATW + k4 * 4);
        *reinterpret_cast<float4*>(&As[r][k4 * 4]) = v;
    }
    __syncthreads();
    float acc[8] = {0.f, 0.f, 0.f, 0.f, 0.f, 0.f, 0.f, 0.f};
    for (int k = 0; k < CATW; k += 4) {
        float w0 = W[(size_t)(k + 0) * HIDW + t];
        float w1 = W[(size_t)(k + 1) * HIDW + t];
        float w2 = W[(size_t)(k + 2) * HIDW + t];
        float w3 = W[(size_t)(k + 3) * HIDW + t];
#pragma unroll
        for (int r = 0; r < 8; ++r) {
            float4 a = *reinterpret_cast<const float4*>(&As[r][k]);
            acc[r] += a.x * w0 + a.y * w1 + a.z * w2 + a.w * w3;
        }
    }
    float bb = b[t];
#pragma unroll
    for (int r = 0; r < 8; ++r)
        o[(size_t)(rb + r) * HIDW + t] = fmaxf(acc[r] + bb, 0.f);
}

// ---------- readout dense1: (2048x256)@(256x128), 16 rows/block ----------
__global__ __launch_bounds__(256)
void k_read1(const float* __restrict__ A, const float* __restrict__ W,
             const float* __restrict__ b, float* __restrict__ o)
{
    __shared__ float As[16][HIDW];
    int t = threadIdx.x;
    int c = t & 127, rh = t >> 7;      // 2 row-halves x 128 cols
    int rb = blockIdx.x * 16;
#pragma unroll
    for (int p = 0; p < 4; ++p) {
        int idx = p * 256 + t;         // float4 index; 16*256/4 = 1024
        int r = idx >> 6, k4 = idx & 63;
        float4 v = *reinterpret_cast<const float4*>(A + (size_t)(rb + r) * HIDW + k4 * 4);
        *reinterpret_cast<float4*>(&As[r][k4 * 4]) = v;
    }
    __syncthreads();
    float acc[8] = {0.f, 0.f, 0.f, 0.f, 0.f, 0.f, 0.f, 0.f};
    for (int k = 0; k < HIDW; k += 4) {
        float w0 = W[(size_t)(k + 0) * DD + c];
        float w1 = W[(size_t)(k + 1) * DD + c];
        float w2 = W[(size_t)(k + 2) * DD + c];
        float w3 = W[(size_t)(k + 3) * DD + c];
#pragma unroll
        for (int r = 0; r < 8; ++r) {
            float4 a = *reinterpret_cast<const float4*>(&As[rh * 8 + r][k]);
            acc[r] += a.x * w0 + a.y * w1 + a.z * w2 + a.w * w3;
        }
    }
    float bb = b[c];
#pragma unroll
    for (int r = 0; r < 8; ++r)
        o[(size_t)(rb + rh * 8 + r) * DD + c] = fmaxf(acc[r] + bb, 0.f);
}

// ---------- final BN + dot with dense2 ----------
__global__ __launch_bounds__(256)
void k_final(const float* __restrict__ g1, const float* __restrict__ mean,
             const float* __restrict__ inv, const float* __restrict__ gam,
             const float* __restrict__ bet, const float* __restrict__ W2,
             const float* __restrict__ b2, float* __restrict__ out)
{
    int w = threadIdx.x >> 6, lane = threadIdx.x & 63;
    int row = blockIdx.x * 4 + w;
    float s = 0.f;
#pragma unroll
    for (int q = 0; q < 2; ++q) {
        int c = lane + q * 64;
        float v = gam[c] * (g1[(size_t)row * DD + c] - mean[c]) * inv[c] + bet[c];
        s += v * W2[c];
    }
#pragma unroll
    for (int off = 32; off > 0; off >>= 1) s += __shfl_down(s, off);
    if (lane == 0) out[row] = s + b2[0];
}

extern "C" void kernel_launch(void* const* d_in, const int* in_sizes, int n_in,
                              void* d_out, int out_size, void* d_ws, size_t ws_size,
                              hipStream_t stream)
{
    const float* x       = (const float*)d_in[0];
    const int*   nbr     = (const int*)d_in[1];
    const int*   mem     = (const int*)d_in[2];
    const float* merge_W = (const float*)d_in[3];
    const float* merge_b = (const float*)d_in[4];
    const float* lin1_W  = (const float*)d_in[5];
    const float* lin1_b  = (const float*)d_in[6];
    const float* lin2_W  = (const float*)d_in[7];
    const float* lin2_b  = (const float*)d_in[8];
    const float* bn_g    = (const float*)d_in[9];
    const float* bn_b    = (const float*)d_in[10];
    const float* epsv    = (const float*)d_in[11];
    const float* d0W     = (const float*)d_in[12];
    const float* d0b     = (const float*)d_in[13];
    const float* d1W     = (const float*)d_in[14];
    const float* d1b     = (const float*)d_in[15];
    const float* bn0g    = (const float*)d_in[16];
    const float* bn0b    = (const float*)d_in[17];
    const float* d2W     = (const float*)d_in[18];
    const float* d2b     = (const float*)d_in[19];
    float* out = (float*)d_out;

    // ---- workspace carve (256B aligned chunks) ----
    char* p = (char*)d_ws;
    auto alloc = [&](size_t bytes) { char* r = p; p += (bytes + 255) & ~(size_t)255; return r; };
    float*  h     = (float*)alloc((size_t)N_NODES * DD * 4);        // fp32 master h
    ushort* hb    = (ushort*)alloc((size_t)N_NODES * DD * 2);       // bf16 mirror
    ushort* Abuf  = (ushort*)alloc((size_t)N_NODES * 2 * DD * 2);   // aggregation A (N x 256 bf16)
    float*  uf    = (float*)alloc((size_t)N_NODES * DD * 4);        // u (lin2 out, fp32)
    float*  G     = (float*)alloc((size_t)NGRAPH * CATW * 4);
    float*  g0    = (float*)alloc((size_t)NGRAPH * HIDW * 4);
    float*  g1    = (float*)alloc((size_t)NGRAPH * DD * 4);
    float*  part  = (float*)alloc((size_t)391 * 256 * 4);
    float*  red   = (float*)alloc(1024 * 4);
    unsigned int* cminb = (unsigned int*)alloc(6 * DD * 4);         // 6 colmin bufs (enc)
    float*  bnacc = (float*)alloc((size_t)NBLOCKS * 2 * DD * 4);    // per-iter BN sums
    ushort* mergeT = (ushort*)alloc((size_t)NBLOCKS * 2 * DD * DD * 2);
    ushort* lin1T  = (ushort*)alloc((size_t)NBLOCKS * DD * HIDW * 2);
    ushort* lin2T  = (ushort*)alloc((size_t)NBLOCKS * HIDW * DD * 2);
    float* meanp  = red + DD;
    float* invp   = red + 2 * DD;

    const int NBP = 391;      // ceil(100000/256)
    const int NRB = 782;      // ceil(100000/128)
    const int NWB = 1563;     // ceil(100000/64) — fused-wave grid (16 rows/wave)

    k_init<<<12500, 256, 0, stream>>>(x, h, hb);
    k_setup<<<1, 256, 0, stream>>>(cminb, bnacc);
    {   // weight convert + transpose (fp32 (K,M) -> bf16 (M,K))
        int tm = NBLOCKS * 2 * DD * DD;
        k_convT<<<(tm + 255) / 256, 256, 0, stream>>>(merge_W, mergeT, 2 * DD, DD, tm);
        int t1 = NBLOCKS * DD * HIDW;
        k_convT<<<(t1 + 255) / 256, 256, 0, stream>>>(lin1_W, lin1T, DD, HIDW, t1);
        int t2 = NBLOCKS * HIDW * DD;
        k_convT<<<(t2 + 255) / 256, 256, 0, stream>>>(lin2_W, lin2T, HIDW, DD, t2);
    }
    hipMemsetAsync(G, 0, (size_t)NGRAPH * CATW * sizeof(float), stream);
    k_colmin_part<<<NBP, 256, 0, stream>>>(x, part, N_NODES);
    k_colmin_fin<<<1, 128, 0, stream>>>(part, cminb, NBP);
    k_scan_x<<<NRB, 256, 0, stream>>>(x, mem, G, N_NODES);

    for (int i = 0; i < NBLOCKS; ++i) {
        k_aggregate_b<<<N_NODES / 16, 256, 0, stream>>>(hb, nbr, cminb + (size_t)i * DD, Abuf);
        k_fused_wave<<<NWB, 256, 0, stream>>>(
            Abuf, h,
            mergeT + (size_t)i * 2 * DD * DD,
            lin1T + (size_t)i * DD * HIDW,
            lin2T + (size_t)i * HIDW * DD,
            merge_b + (size_t)i * DD, lin1_b + (size_t)i * HIDW, lin2_b + (size_t)i * DD,
            epsv + i, uf, bnacc + (size_t)i * 2 * DD);
        k_bn_fin<<<1, 128, 0, stream>>>(bnacc + (size_t)i * 2 * DD, 1, 1.f / (float)N_NODES, meanp, invp);
        k_bn_apply_scan<<<NRB, 256, 0, stream>>>(uf, h, hb, meanp, invp,
                                                 bn_g + (size_t)i * DD, bn_b + (size_t)i * DD,
                                                 mem, G, cminb + (size_t)(i + 1) * DD,
                                                 (i + 1) * DD, N_NODES);
    }

    // readout MLP — fp32, high-parallelism row-strip kernels
    k_read0<<<NGRAPH / 8, 256, 0, stream>>>(G, d0W, d0b, g0);
    k_read1<<<NGRAPH / 16, 256, 0, stream>>>(g0, d1W, d1b, g1);
    k_bn_part<<<8, 256, 0, stream>>>(g1, part, NGRAPH);
    k_bn_fin<<<1, 128, 0, stream>>>(part, 8, 1.f / (float)NGRAPH, meanp, invp);
    k_final<<<NGRAPH / 4, 256, 0, stream>>>(g1, meanp, invp, bn0g, bn0b, d2W, d2b, out);
}

// Round 8
// 1328.041 us; speedup vs baseline: 1.7741x; 1.7741x over previous
//
#include <hip/hip_runtime.h>
#include <hip/hip_bf16.h>
#include <math.h>

#define N_NODES 100000
#define DD 128
#define MAXDEG 16
#define HIDW 256
#define NBLOCKS 5
#define NGRAPH 2048
#define CATW 768   // D*(BLOCKS+1)

typedef __attribute__((ext_vector_type(8))) short short8;
typedef __attribute__((ext_vector_type(4))) float f32x4;

__device__ __forceinline__ float b2f(ushort u) {
    union { unsigned int i; float f; } x; x.i = ((unsigned int)u) << 16; return x.f;
}
__device__ __forceinline__ ushort f2b(float f) {
    unsigned int x = __float_as_uint(f);
    unsigned int r = (x + 0x7fffu + ((x >> 16) & 1u)) >> 16;
    return (ushort)r;
}
// order-preserving float<->uint for atomicMin
__device__ __forceinline__ unsigned int encf(float f) {
    unsigned int b = __float_as_uint(f);
    return (b & 0x80000000u) ? ~b : (b | 0x80000000u);
}
__device__ __forceinline__ float decf(unsigned int e) {
    return __uint_as_float((e & 0x80000000u) ? (e & 0x7fffffffu) : ~e);
}

// ---------- init: h = x (fp32), hb = bf16(x) ----------
__global__ __launch_bounds__(256)
void k_init(const float* __restrict__ x, float* __restrict__ h, ushort* __restrict__ hb)
{
    size_t i = ((size_t)blockIdx.x * 256 + threadIdx.x) * 4;
    float4 v = *reinterpret_cast<const float4*>(x + i);
    *reinterpret_cast<float4*>(h + i) = v;
    ushort4 u;
    u.x = f2b(v.x); u.y = f2b(v.y); u.z = f2b(v.z); u.w = f2b(v.w);
    *reinterpret_cast<ushort4*>(hb + i) = u;
}

// ---------- setup: colmin bufs to +inf(enc), bn accumulators to 0 ----------
__global__ void k_setup(unsigned int* __restrict__ cmin, float* __restrict__ bnacc)
{
    int t = threadIdx.x;
    for (int i = t; i < 6 * DD; i += 256) cmin[i] = 0xFF800000u;  // enc(+inf)
    for (int i = t; i < NBLOCKS * 2 * DD; i += 256) bnacc[i] = 0.f;
}

// ---------- batched convert + transpose: src (cnt,K,M) fp32 -> dst (cnt,M,K) bf16 ----------
__global__ __launch_bounds__(256)
void k_convT(const float* __restrict__ src, ushort* __restrict__ dst, int K, int M, int total)
{
    int id = blockIdx.x * 256 + threadIdx.x;
    if (id >= total) return;
    int km = K * M;
    int b = id / km, rem = id - b * km;
    int m = rem / K, k = rem - m * K;
    dst[(size_t)b * km + (size_t)m * K + k] = f2b(src[(size_t)b * km + (size_t)k * M + m]);
}

// ---------- column min over rows of x (fp32, startup only) ----------
__global__ __launch_bounds__(256)
void k_colmin_part(const float* __restrict__ h, float* __restrict__ part, int nrows)
{
    int t = threadIdx.x;
    int c = t & 127, half = t >> 7;
    int r0 = blockIdx.x * 256;
    int rend = r0 + 256; if (rend > nrows) rend = nrows;
    float m = INFINITY;
    for (int r = r0 + half; r < rend; r += 2)
        m = fminf(m, h[(size_t)r * DD + c]);
    __shared__ float sm[256];
    sm[t] = m;
    __syncthreads();
    if (half == 0) part[(size_t)blockIdx.x * DD + c] = fminf(sm[c], sm[c + 128]);
}

__global__ void k_colmin_fin(const float* __restrict__ part, unsigned int* __restrict__ colmin, int nb)
{
    int c = threadIdx.x; // 128 threads
    float m = INFINITY;
    for (int b = 0; b < nb; ++b) m = fminf(m, part[(size_t)b * DD + c]);
    colmin[c] = encf(m);
}

// ---------- aggregation (bf16): 16 nodes/block, 16 lanes/node, 8 cols/lane ----------
__global__ __launch_bounds__(256)
void k_aggregate_b(const ushort* __restrict__ hb, const int* __restrict__ nbr,
                   const unsigned int* __restrict__ cmin, ushort* __restrict__ A)
{
    int t = threadIdx.x;
    int node = blockIdx.x * 16 + (t >> 4);
    int c0 = (t & 15) * 8;
    const int* row = nbr + (size_t)node * MAXDEG;
    float s[8], mx[8];
#pragma unroll
    for (int q = 0; q < 8; ++q) { s[q] = 0.f; mx[q] = -INFINITY; }
    int cnt = 0;
#pragma unroll
    for (int j = 0; j < MAXDEG; ++j) {
        int id = row[j];
        if (id >= 0) {
            uint4 v = *reinterpret_cast<const uint4*>(hb + (size_t)id * DD + c0);
            unsigned int w0 = v.x, w1 = v.y, w2 = v.z, w3 = v.w;
            float f0 = __uint_as_float(w0 << 16),  f1 = __uint_as_float(w0 & 0xffff0000u);
            float f2 = __uint_as_float(w1 << 16),  f3 = __uint_as_float(w1 & 0xffff0000u);
            float f4 = __uint_as_float(w2 << 16),  f5 = __uint_as_float(w2 & 0xffff0000u);
            float f6 = __uint_as_float(w3 << 16),  f7 = __uint_as_float(w3 & 0xffff0000u);
            s[0] += f0; s[1] += f1; s[2] += f2; s[3] += f3;
            s[4] += f4; s[5] += f5; s[6] += f6; s[7] += f7;
            mx[0] = fmaxf(mx[0], f0); mx[1] = fmaxf(mx[1], f1);
            mx[2] = fmaxf(mx[2], f2); mx[3] = fmaxf(mx[3], f3);
            mx[4] = fmaxf(mx[4], f4); mx[5] = fmaxf(mx[5], f5);
            mx[6] = fmaxf(mx[6], f6); mx[7] = fmaxf(mx[7], f7);
            ++cnt;
        }
    }
    if (cnt == 0) {
#pragma unroll
        for (int q = 0; q < 8; ++q) mx[q] = decf(cmin[c0 + q]);
    }
    short8 vs, vm;
#pragma unroll
    for (int q = 0; q < 8; ++q) { vs[q] = (short)f2b(s[q]); vm[q] = (short)f2b(mx[q]); }
    *reinterpret_cast<short8*>(A + (size_t)node * (2 * DD) + c0) = vs;
    *reinterpret_cast<short8*>(A + (size_t)node * (2 * DD) + DD + c0) = vm;
}

// ---------- block-fused MLP: 64-row tile, 4 waves, 48KB LDS, B/C interleaved per 64-hid ----------
// LDS: As 8K | Bs 16K (weight chunks) | Zs 16K | Ts 8K = 48KB -> 3 blocks/CU.
__global__ __launch_bounds__(256, 3)
void k_fused_mlp(const ushort* __restrict__ Ag, const float* __restrict__ h,
                 const ushort* __restrict__ mW, const ushort* __restrict__ w1,
                 const ushort* __restrict__ w2, const float* __restrict__ mb,
                 const float* __restrict__ b1, const float* __restrict__ b2,
                 const float* __restrict__ eps_ptr, float* __restrict__ uf,
                 float* __restrict__ bnacc)
{
    __shared__ __align__(16) char pool[48 * 1024];
    char* As = pool;                 // 8KB  [64][64] bf16
    char* Bs = pool + 8 * 1024;      // 16KB weight chunk staging
    char* Zs = pool + 24 * 1024;     // 16KB [64][128] bf16
    char* Ts = pool + 40 * 1024;     // 8KB  [64][64] bf16

    const int t = threadIdx.x;
    const int lane = t & 63, wave = t >> 6;      // 4 waves
    const int lr = lane & 15;
    const int lg = lane >> 4;                    // 0..3
    const int lkb = lg << 4;                     // 16B k-offset within 64B k32 chunk
    const int rb = blockIdx.x * 64;
    const float alpha = 1.f + *eps_ptr;

    // ---------------- phase A: z(64x128) = Ag(64x256) @ mW^T ----------------
    f32x4 acc[4][2];
#pragma unroll
    for (int m = 0; m < 4; ++m)
#pragma unroll
        for (int n = 0; n < 2; ++n) acc[m][n] = (f32x4)(0.f);

    for (int k0 = 0; k0 < 256; k0 += 64) {
#pragma unroll
        for (int p = 0; p < 2; ++p) {            // As: 64 rows x 64 k
            int idx = p * 256 + t, row = idx >> 3, ch = idx & 7;
            int gr = rb + row;
            short8 v = {};
            if (gr < N_NODES)
                v = *reinterpret_cast<const short8*>(Ag + (size_t)gr * 256 + k0 + ch * 8);
            int byte = (row << 7) | (ch << 4); byte ^= (row & 7) << 4;
            *reinterpret_cast<short8*>(As + byte) = v;
        }
#pragma unroll
        for (int p = 0; p < 4; ++p) {            // Bs: mW 128 rows x 64 k
            int idx = p * 256 + t, row = idx >> 3, ch = idx & 7;
            short8 v = *reinterpret_cast<const short8*>(mW + (size_t)row * 256 + k0 + ch * 8);
            int byte = (row << 7) | (ch << 4); byte ^= (row & 7) << 4;
            *reinterpret_cast<short8*>(Bs + byte) = v;
        }
        __syncthreads();
#pragma unroll
        for (int k32 = 0; k32 < 2; ++k32) {
            short8 af[4], bq[2];
#pragma unroll
            for (int m = 0; m < 4; ++m) {
                int row = m * 16 + lr;
                int byte = (row << 7) | (k32 * 64 + lkb); byte ^= (row & 7) << 4;
                af[m] = *reinterpret_cast<const short8*>(As + byte);
            }
#pragma unroll
            for (int n = 0; n < 2; ++n) {
                int col = wave * 32 + n * 16 + lr;
                int byte = (col << 7) | (k32 * 64 + lkb); byte ^= (col & 7) << 4;
                bq[n] = *reinterpret_cast<const short8*>(Bs + byte);
            }
#pragma unroll
            for (int m = 0; m < 4; ++m)
#pragma unroll
                for (int n = 0; n < 2; ++n)
                    acc[m][n] = __builtin_amdgcn_mfma_f32_16x16x32_bf16(af[m], bq[n], acc[m][n], 0, 0, 0);
        }
        __syncthreads();
    }
    {   // epilogue A -> Zs (bf16, swizzled)
#pragma unroll
        for (int m = 0; m < 4; ++m)
#pragma unroll
            for (int j = 0; j < 4; ++j) {
                int lrow = m * 16 + lg * 4 + j;
                int grow = rb + lrow;
#pragma unroll
                for (int n = 0; n < 2; ++n) {
                    int col = wave * 32 + n * 16 + lr;
                    float z = acc[m][n][j] + mb[col];
                    if (grow < N_NODES) z += alpha * h[(size_t)grow * DD + col];
                    int byte = (lrow << 8) | (col << 1); byte ^= (lrow & 7) << 4;
                    *reinterpret_cast<ushort*>(Zs + byte) = f2b(z);
                }
            }
    }
    __syncthreads();

    // ---------------- phases B+C interleaved per 64-hid chunk ----------------
    f32x4 au[4][2];
#pragma unroll
    for (int m = 0; m < 4; ++m)
#pragma unroll
        for (int n = 0; n < 2; ++n) au[m][n] = (f32x4)(0.f);

    for (int hc = 0; hc < 4; ++hc) {
        // stage w1 chunk [64 hid][128 k] -> Bs
#pragma unroll
        for (int p = 0; p < 4; ++p) {
            int idx = p * 256 + t, row = idx >> 4, ch = idx & 15;
            short8 v = *reinterpret_cast<const short8*>(w1 + (size_t)(hc * 64 + row) * 128 + ch * 8);
            int byte = (row << 8) | (ch << 4); byte ^= (row & 7) << 4;
            *reinterpret_cast<short8*>(Bs + byte) = v;
        }
        __syncthreads();
        // B: t_chunk(64x64) = relu(z(64x128) @ w1chunk^T + b1)
        f32x4 at[4];
#pragma unroll
        for (int m = 0; m < 4; ++m) at[m] = (f32x4)(0.f);
#pragma unroll
        for (int kc = 0; kc < 4; ++kc) {
            int wrow = wave * 16 + lr;
            int bbyte = (wrow << 8) | (kc * 64 + lkb); bbyte ^= (wrow & 7) << 4;
            short8 bq = *reinterpret_cast<const short8*>(Bs + bbyte);
#pragma unroll
            for (int m = 0; m < 4; ++m) {
                int row = m * 16 + lr;
                int byte = (row << 8) | (kc * 64 + lkb); byte ^= (row & 7) << 4;
                short8 az = *reinterpret_cast<const short8*>(Zs + byte);
                at[m] = __builtin_amdgcn_mfma_f32_16x16x32_bf16(az, bq, at[m], 0, 0, 0);
            }
        }
        // t chunk -> Ts (bf16, swizzled)
#pragma unroll
        for (int m = 0; m < 4; ++m)
#pragma unroll
            for (int j = 0; j < 4; ++j) {
                int lrow = m * 16 + lg * 4 + j;
                int hidc = wave * 16 + lr;
                float tv = fmaxf(at[m][j] + b1[hc * 64 + hidc], 0.f);
                int byte = (lrow << 7) | (hidc << 1); byte ^= (lrow & 7) << 4;
                *reinterpret_cast<ushort*>(Ts + byte) = f2b(tv);
            }
        __syncthreads();
        // stage w2 chunk [128 out][64 k] -> Bs
#pragma unroll
        for (int p = 0; p < 4; ++p) {
            int idx = p * 256 + t, row = idx >> 3, ch = idx & 7;
            short8 v = *reinterpret_cast<const short8*>(w2 + (size_t)row * 256 + hc * 64 + ch * 8);
            int byte = (row << 7) | (ch << 4); byte ^= (row & 7) << 4;
            *reinterpret_cast<short8*>(Bs + byte) = v;
        }
        __syncthreads();
        // C: au += t_chunk @ w2chunk^T
#pragma unroll
        for (int k32 = 0; k32 < 2; ++k32) {
            short8 atf[4], bq[2];
#pragma unroll
            for (int m = 0; m < 4; ++m) {
                int row = m * 16 + lr;
                int byte = (row << 7) | (k32 * 64 + lkb); byte ^= (row & 7) << 4;
                atf[m] = *reinterpret_cast<const short8*>(Ts + byte);
            }
#pragma unroll
            for (int n = 0; n < 2; ++n) {
                int wrow = wave * 32 + n * 16 + lr;
                int byte = (wrow << 7) | (k32 * 64 + lkb); byte ^= (wrow & 7) << 4;
                bq[n] = *reinterpret_cast<const short8*>(Bs + byte);
            }
#pragma unroll
            for (int m = 0; m < 4; ++m)
#pragma unroll
                for (int n = 0; n < 2; ++n)
                    au[m][n] = __builtin_amdgcn_mfma_f32_16x16x32_bf16(atf[m], bq[n], au[m][n], 0, 0, 0);
        }
        __syncthreads();
    }

    // ---- epilogue C: u store (fp32) + BN partial sums ----
    float e1[2] = {0.f, 0.f}, e2[2] = {0.f, 0.f};
#pragma unroll
    for (int m = 0; m < 4; ++m)
#pragma unroll
        for (int j = 0; j < 4; ++j) {
            int grow = rb + m * 16 + lg * 4 + j;
            if (grow >= N_NODES) continue;
#pragma unroll
            for (int n = 0; n < 2; ++n) {
                int col = wave * 32 + n * 16 + lr;
                float u = fmaxf(au[m][n][j] + b2[col], 0.f);
                uf[(size_t)grow * DD + col] = u;
                e1[n] += u; e2[n] += u * u;
            }
        }
#pragma unroll
    for (int n = 0; n < 2; ++n) {
        int col = wave * 32 + n * 16 + lr;
        float a = e1[n], b = e2[n];
        a += __shfl_xor(a, 16); b += __shfl_xor(b, 16);
        a += __shfl_xor(a, 32); b += __shfl_xor(b, 32);
        if (lg == 0) {
            atomicAdd(&bnacc[col], a);
            atomicAdd(&bnacc[128 + col], b);
        }
    }
}

__global__ void k_bn_fin(const float* __restrict__ part, int nb, float inv_n,
                         float* __restrict__ mean, float* __restrict__ inv)
{
    int c = threadIdx.x; // 128 threads
    float s1 = 0.f, s2 = 0.f;
    for (int b = 0; b < nb; ++b) {
        s1 += part[(size_t)b * 256 + c];
        s2 += part[(size_t)b * 256 + 128 + c];
    }
    float m = s1 * inv_n;
    float v = s2 * inv_n - m * m;
    mean[c] = m;
    inv[c] = rsqrtf(v + 1e-5f);
}

// ---------- BN apply + h update + hb mirror + colmin(next) + segmented scan into G ----------
__global__ __launch_bounds__(256)
void k_bn_apply_scan(const float* __restrict__ u, float* __restrict__ h,
                     ushort* __restrict__ hb,
                     const float* __restrict__ mean, const float* __restrict__ inv,
                     const float* __restrict__ gam, const float* __restrict__ bet,
                     const int* __restrict__ mem, float* __restrict__ G,
                     unsigned int* __restrict__ cmin_next,
                     int colbase, int nrows)
{
    int t = threadIdx.x;
    int c = t & 127, half = t >> 7;
    int r0 = blockIdx.x * 128;
    int rend = r0 + 128; if (rend > nrows) rend = nrows;
    float mu = mean[c], iv = inv[c], g = gam[c], b = bet[c];
    float accv = 0.f, lmin = INFINITY;
    int curg = -1;
    for (int r = r0 + half; r < rend; r += 2) {
        float z = g * (u[(size_t)r * DD + c] - mu) * iv + b;
        float hn = h[(size_t)r * DD + c] + z;
        h[(size_t)r * DD + c] = hn;
        hb[(size_t)r * DD + c] = f2b(hn);
        lmin = fminf(lmin, hn);
        int gg = mem[r];
        if (gg != curg) {
            if (curg >= 0) atomicAdd(&G[(size_t)curg * CATW + colbase + c], accv);
            curg = gg; accv = 0.f;
        }
        accv += z;
    }
    if (curg >= 0) atomicAdd(&G[(size_t)curg * CATW + colbase + c], accv);
    __shared__ float sm[256];
    sm[t] = lmin;
    __syncthreads();
    if (half == 0) atomicMin(&cmin_next[c], encf(fminf(sm[c], sm[c + 128])));
}

// ---------- segmented scan-add of x (fp32) into G cols [0,128) ----------
__global__ __launch_bounds__(256)
void k_scan_x(const float* __restrict__ x, const int* __restrict__ mem,
              float* __restrict__ G, int nrows)
{
    int t = threadIdx.x;
    int c = t & 127, half = t >> 7;
    int r0 = blockIdx.x * 128;
    int rend = r0 + 128; if (rend > nrows) rend = nrows;
    float accv = 0.f;
    int curg = -1;
    for (int r = r0 + half; r < rend; r += 2) {
        float z = x[(size_t)r * DD + c];
        int gg = mem[r];
        if (gg != curg) {
            if (curg >= 0) atomicAdd(&G[(size_t)curg * CATW + c], accv);
            curg = gg; accv = 0.f;
        }
        accv += z;
    }
    if (curg >= 0) atomicAdd(&G[(size_t)curg * CATW + c], accv);
}

// ---------- BN stats partials from fp32 (readout path) ----------
__global__ __launch_bounds__(256)
void k_bn_part(const float* __restrict__ u, float* __restrict__ part, int nrows)
{
    int t = threadIdx.x;
    int c = t & 127, half = t >> 7;
    int r0 = blockIdx.x * 256;
    int rend = r0 + 256; if (rend > nrows) rend = nrows;
    float s1 = 0.f, s2 = 0.f;
    for (int r = r0 + half; r < rend; r += 2) {
        float v = u[(size_t)r * DD + c];
        s1 += v; s2 += v * v;
    }
    __shared__ float sh1[256], sh2[256];
    sh1[t] = s1; sh2[t] = s2;
    __syncthreads();
    if (half == 0) {
        part[(size_t)blockIdx.x * 256 + c]       = sh1[c] + sh1[c + 128];
        part[(size_t)blockIdx.x * 256 + 128 + c] = sh2[c] + sh2[c + 128];
    }
}

// ---------- readout dense0: (2048x768)@(768x256), 8 rows/block ----------
__global__ __launch_bounds__(256)
void k_read0(const float* __restrict__ G, const float* __restrict__ W,
             const float* __restrict__ b, float* __restrict__ o)
{
    __shared__ float As[8][CATW];
    int t = threadIdx.x;
    int rb = blockIdx.x * 8;
#pragma unroll
    for (int p = 0; p < 6; ++p) {
        int idx = p * 256 + t;         // float4 index; 8*768/4 = 1536
        int r = idx / 192, k4 = idx - r * 192;
        float4 v = *reinterpret_cast<const float4*>(G + (size_t)(rb + r) * CATW + k4 * 4);
        *reinterpret_cast<float4*>(&As[r][k4 * 4]) = v;
    }
    __syncthreads();
    float acc[8] = {0.f, 0.f, 0.f, 0.f, 0.f, 0.f, 0.f, 0.f};
    for (int k = 0; k < CATW; k += 4) {
        float w0 = W[(size_t)(k + 0) * HIDW + t];
        float w1 = W[(size_t)(k + 1) * HIDW + t];
        float w2 = W[(size_t)(k + 2) * HIDW + t];
        float w3 = W[(size_t)(k + 3) * HIDW + t];
#pragma unroll
        for (int r = 0; r < 8; ++r) {
            float4 a = *reinterpret_cast<const float4*>(&As[r][k]);
            acc[r] += a.x * w0 + a.y * w1 + a.z * w2 + a.w * w3;
        }
    }
    float bb = b[t];
#pragma unroll
    for (int r = 0; r < 8; ++r)
        o[(size_t)(rb + r) * HIDW + t] = fmaxf(acc[r] + bb, 0.f);
}

// ---------- readout dense1: (2048x256)@(256x128), 16 rows/block ----------
__global__ __launch_bounds__(256)
void k_read1(const float* __restrict__ A, const float* __restrict__ W,
             const float* __restrict__ b, float* __restrict__ o)
{
    __shared__ float As[16][HIDW];
    int t = threadIdx.x;
    int c = t & 127, rh = t >> 7;      // 2 row-halves x 128 cols
    int rb = blockIdx.x * 16;
#pragma unroll
    for (int p = 0; p < 4; ++p) {
        int idx = p * 256 + t;         // float4 index; 16*256/4 = 1024
        int r = idx >> 6, k4 = idx & 63;
        float4 v = *reinterpret_cast<const float4*>(A + (size_t)(rb + r) * HIDW + k4 * 4);
        *reinterpret_cast<float4*>(&As[r][k4 * 4]) = v;
    }
    __syncthreads();
    float acc[8] = {0.f, 0.f, 0.f, 0.f, 0.f, 0.f, 0.f, 0.f};
    for (int k = 0; k < HIDW; k += 4) {
        float w0 = W[(size_t)(k + 0) * DD + c];
        float w1 = W[(size_t)(k + 1) * DD + c];
        float w2 = W[(size_t)(k + 2) * DD + c];
        float w3 = W[(size_t)(k + 3) * DD + c];
#pragma unroll
        for (int r = 0; r < 8; ++r) {
            float4 a = *reinterpret_cast<const float4*>(&As[rh * 8 + r][k]);
            acc[r] += a.x * w0 + a.y * w1 + a.z * w2 + a.w * w3;
        }
    }
    float bb = b[c];
#pragma unroll
    for (int r = 0; r < 8; ++r)
        o[(size_t)(rb + rh * 8 + r) * DD + c] = fmaxf(acc[r] + bb, 0.f);
}

// ---------- final BN + dot with dense2 ----------
__global__ __launch_bounds__(256)
void k_final(const float* __restrict__ g1, const float* __restrict__ mean,
             const float* __restrict__ inv, const float* __restrict__ gam,
             const float* __restrict__ bet, const float* __restrict__ W2,
             const float* __restrict__ b2, float* __restrict__ out)
{
    int w = threadIdx.x >> 6, lane = threadIdx.x & 63;
    int row = blockIdx.x * 4 + w;
    float s = 0.f;
#pragma unroll
    for (int q = 0; q < 2; ++q) {
        int c = lane + q * 64;
        float v = gam[c] * (g1[(size_t)row * DD + c] - mean[c]) * inv[c] + bet[c];
        s += v * W2[c];
    }
#pragma unroll
    for (int off = 32; off > 0; off >>= 1) s += __shfl_down(s, off);
    if (lane == 0) out[row] = s + b2[0];
}

extern "C" void kernel_launch(void* const* d_in, const int* in_sizes, int n_in,
                              void* d_out, int out_size, void* d_ws, size_t ws_size,
                              hipStream_t stream)
{
    const float* x       = (const float*)d_in[0];
    const int*   nbr     = (const int*)d_in[1];
    const int*   mem     = (const int*)d_in[2];
    const float* merge_W = (const float*)d_in[3];
    const float* merge_b = (const float*)d_in[4];
    const float* lin1_W  = (const float*)d_in[5];
    const float* lin1_b  = (const float*)d_in[6];
    const float* lin2_W  = (const float*)d_in[7];
    const float* lin2_b  = (const float*)d_in[8];
    const float* bn_g    = (const float*)d_in[9];
    const float* bn_b    = (const float*)d_in[10];
    const float* epsv    = (const float*)d_in[11];
    const float* d0W     = (const float*)d_in[12];
    const float* d0b     = (const float*)d_in[13];
    const float* d1W     = (const float*)d_in[14];
    const float* d1b     = (const float*)d_in[15];
    const float* bn0g    = (const float*)d_in[16];
    const float* bn0b    = (const float*)d_in[17];
    const float* d2W     = (const float*)d_in[18];
    const float* d2b     = (const float*)d_in[19];
    float* out = (float*)d_out;

    // ---- workspace carve (256B aligned chunks) ----
    char* p = (char*)d_ws;
    auto alloc = [&](size_t bytes) { char* r = p; p += (bytes + 255) & ~(size_t)255; return r; };
    float*  h     = (float*)alloc((size_t)N_NODES * DD * 4);        // fp32 master h
    ushort* hb    = (ushort*)alloc((size_t)N_NODES * DD * 2);       // bf16 mirror
    ushort* Abuf  = (ushort*)alloc((size_t)N_NODES * 2 * DD * 2);   // aggregation A (N x 256 bf16)
    float*  uf    = (float*)alloc((size_t)N_NODES * DD * 4);        // u (lin2 out, fp32)
    float*  G     = (float*)alloc((size_t)NGRAPH * CATW * 4);
    float*  g0    = (float*)alloc((size_t)NGRAPH * HIDW * 4);
    float*  g1    = (float*)alloc((size_t)NGRAPH * DD * 4);
    float*  part  = (float*)alloc((size_t)391 * 256 * 4);
    float*  red   = (float*)alloc(1024 * 4);
    unsigned int* cminb = (unsigned int*)alloc(6 * DD * 4);         // 6 colmin bufs (enc)
    float*  bnacc = (float*)alloc((size_t)NBLOCKS * 2 * DD * 4);    // per-iter BN sums
    ushort* mergeT = (ushort*)alloc((size_t)NBLOCKS * 2 * DD * DD * 2);
    ushort* lin1T  = (ushort*)alloc((size_t)NBLOCKS * DD * HIDW * 2);
    ushort* lin2T  = (ushort*)alloc((size_t)NBLOCKS * HIDW * DD * 2);
    float* meanp  = red + DD;
    float* invp   = red + 2 * DD;

    const int NBP = 391;      // ceil(100000/256)
    const int NRB = 782;      // ceil(100000/128)
    const int NFB = 1563;     // ceil(100000/64) — fused tile grid

    k_init<<<12500, 256, 0, stream>>>(x, h, hb);
    k_setup<<<1, 256, 0, stream>>>(cminb, bnacc);
    {   // weight convert + transpose (fp32 (K,M) -> bf16 (M,K))
        int tm = NBLOCKS * 2 * DD * DD;
        k_convT<<<(tm + 255) / 256, 256, 0, stream>>>(merge_W, mergeT, 2 * DD, DD, tm);
        int t1 = NBLOCKS * DD * HIDW;
        k_convT<<<(t1 + 255) / 256, 256, 0, stream>>>(lin1_W, lin1T, DD, HIDW, t1);
        int t2 = NBLOCKS * HIDW * DD;
        k_convT<<<(t2 + 255) / 256, 256, 0, stream>>>(lin2_W, lin2T, HIDW, DD, t2);
    }
    hipMemsetAsync(G, 0, (size_t)NGRAPH * CATW * sizeof(float), stream);
    k_colmin_part<<<NBP, 256, 0, stream>>>(x, part, N_NODES);
    k_colmin_fin<<<1, 128, 0, stream>>>(part, cminb, NBP);
    k_scan_x<<<NRB, 256, 0, stream>>>(x, mem, G, N_NODES);

    for (int i = 0; i < NBLOCKS; ++i) {
        k_aggregate_b<<<N_NODES / 16, 256, 0, stream>>>(hb, nbr, cminb + (size_t)i * DD, Abuf);
        k_fused_mlp<<<NFB, 256, 0, stream>>>(
            Abuf, h,
            mergeT + (size_t)i * 2 * DD * DD,
            lin1T + (size_t)i * DD * HIDW,
            lin2T + (size_t)i * HIDW * DD,
            merge_b + (size_t)i * DD, lin1_b + (size_t)i * HIDW, lin2_b + (size_t)i * DD,
            epsv + i, uf, bnacc + (size_t)i * 2 * DD);
        k_bn_fin<<<1, 128, 0, stream>>>(bnacc + (size_t)i * 2 * DD, 1, 1.f / (float)N_NODES, meanp, invp);
        k_bn_apply_scan<<<NRB, 256, 0, stream>>>(uf, h, hb, meanp, invp,
                                                 bn_g + (size_t)i * DD, bn_b + (size_t)i * DD,
                                                 mem, G, cminb + (size_t)(i + 1) * DD,
                                                 (i + 1) * DD, N_NODES);
    }

    // readout MLP — fp32, high-parallelism row-strip kernels
    k_read0<<<NGRAPH / 8, 256, 0, stream>>>(G, d0W, d0b, g0);
    k_read1<<<NGRAPH / 16, 256, 0, stream>>>(g0, d1W, d1b, g1);
    k_bn_part<<<8, 256, 0, stream>>>(g1, part, NGRAPH);
    k_bn_fin<<<1, 128, 0, stream>>>(part, 8, 1.f / (float)NGRAPH, meanp, invp);
    k_final<<<NGRAPH / 4, 256, 0, stream>>>(g1, meanp, invp, bn0g, bn0b, d2W, d2b, out);
}